// Round 18
// baseline (3499.417 us; speedup 1.0000x reference)
//
#include <hip/hip_runtime.h>
#include <math.h>

// RNN: L=512, B=128, D=512, H=1024, fp32 in/out.
//   xproj = x @ Wx^T + bx -> d_out;  h_t = tanh(xp_t + h_{t-1} @ Wh^T) in place.
// Precision: split-bf16 (hi+lo), 3 MFMAs per product => ~fp32 accuracy.
// Round 18 = R17 with the A-burst forced into FULL flight:
//  - R17's VGPR_Count=60 < 64 payload regs proves the compiler still splits
//    the 16-load burst into 2-3 serialized L3 rounds (~0.4-0.8us/step).
//  - Fix: ONE asm block, 4 base addrs x 4 offset:{0,64,128,192} immediates,
//    16 global_load_dwordx4 sc0sc1 back-to-back, one vmcnt(0), all outputs
//    early-clobber -> 64 payload VGPRs provably live at once.
//  - __launch_bounds__(512,1): 256 blocks on 256 CUs is already 1 block/CU;
//    the old (512,2) cap of 128 VGPR bought nothing and would force spills.

#define L_SEQ 512
#define B_SZ  128
#define D_SZ  512
#define H_SZ  1024
#define BH    (B_SZ * H_SZ)   // 131072

typedef __bf16 bf16x8 __attribute__((ext_vector_type(8)));
typedef float  f32x4  __attribute__((ext_vector_type(4)));
typedef unsigned int uint;
typedef unsigned short ushort;

union V8 { bf16x8 b; ushort u[8]; uint w[4]; };

__device__ __forceinline__ ushort f2bf(float f) {
  uint u = __float_as_uint(f);
  u += 0x7FFFu + ((u >> 16) & 1u);   // round-to-nearest-even
  return (ushort)(u >> 16);
}
__device__ __forceinline__ float bf2f(ushort s) {
  return __uint_as_float(((uint)s) << 16);
}

// tanh(x) = 1 - 2/(e^{2x}+1); v_exp_f32(2^x) + v_rcp_f32. Saturates right.
__device__ __forceinline__ float fast_tanh(float x) {
  float e;
  asm("v_exp_f32 %0, %1" : "=v"(e) : "v"(x * 2.885390081777927f));
  float r;
  asm("v_rcp_f32 %0, %1" : "=v"(r) : "v"(e + 1.0f));
  return 1.0f - 2.0f * r;
}

__device__ __forceinline__ void stg2_sc(ushort* p, uint v) {
  asm volatile("global_store_short %0, %1, off sc0 sc1"
               :: "v"(p), "v"(v) : "memory");
}
__device__ __forceinline__ void stg4_sc(uint* p, uint v) {
  asm volatile("global_store_dword %0, %1, off sc0 sc1"
               :: "v"(p), "v"(v) : "memory");
}

// ---- d_ws layout (ushort elements unless noted) ----
#define WS_WHH 0            // [1024][1024]
#define WS_WHL 1048576      // [1024][1024]
#define WS_WXH 2097152      // [1024][512]
#define WS_WXL 2621440      // [1024][512]
#define WS_HB  3145728      // [2 parity][2 hi/lo][BH] ushort
#define WS_CNT 3670016      // flags: [4 mb][64 nb] u32 (zeroed per launch)

// Split fp32 weights into bf16 hi + bf16 lo(residual); zero flags.
__global__ void split_kernel(const float* __restrict__ Wh,
                             const float* __restrict__ Wx,
                             ushort* __restrict__ ws,
                             uint* __restrict__ flags) {
  if (blockIdx.x == 0) {
    for (int i = threadIdx.x; i < 512; i += 256) flags[i] = 0u;
  }
  const int total = 1048576 + 524288;
  for (int i = blockIdx.x * blockDim.x + threadIdx.x; i < total;
       i += gridDim.x * blockDim.x) {
    const float* src; ushort *dh, *dl; int j;
    if (i < 1048576) { src = Wh; dh = ws + WS_WHH; dl = ws + WS_WHL; j = i; }
    else             { src = Wx; dh = ws + WS_WXH; dl = ws + WS_WXL; j = i - 1048576; }
    float v = src[j];
    ushort h = f2bf(v);
    dh[j] = h;
    dl[j] = f2bf(v - bf2f(h));
  }
}

// xproj v2 (R17): BM=128, BN=256; 2048 blocks x 512 thr; 48 MFMAs/chunk.
__global__ __launch_bounds__(512) void xproj_kernel(
    const float* __restrict__ x,             // [65536][512]
    const ushort* __restrict__ wxh,          // [1024][512]
    const ushort* __restrict__ wxl,
    const float* __restrict__ bx,            // [1024]
    float* __restrict__ out)                 // [65536][1024]
{
  const int bid = blockIdx.x;
  const int bn = bid & 3;
  const int bm = bid >> 2;
  const int tid = threadIdx.x;
  const int w = tid >> 6, l = tid & 63;
  const int wm = w & 1, wn = w >> 1;
  const int lr = l & 15, lk = (l >> 4) * 8;
  const int mbase = bm * 128 + wm * 64;
  const int nbase = bn * 256 + wn * 64;

  f32x4 acc[4][4] = {};

  for (int k0 = 0; k0 < 512; k0 += 32) {
    bf16x8 ah[4], al[4], bh[4], bl[4];
#pragma unroll
    for (int i = 0; i < 4; ++i) {
      const float* ap = x + (size_t)(mbase + i * 16 + lr) * 512 + k0 + lk;
      float4 v0 = *reinterpret_cast<const float4*>(ap);
      float4 v1 = *reinterpret_cast<const float4*>(ap + 4);
      float vv[8] = {v0.x, v0.y, v0.z, v0.w, v1.x, v1.y, v1.z, v1.w};
      V8 hh, ll;
#pragma unroll
      for (int e = 0; e < 8; ++e) {
        ushort hb = f2bf(vv[e]);
        hh.u[e] = hb;
        ll.u[e] = f2bf(vv[e] - bf2f(hb));
      }
      ah[i] = hh.b; al[i] = ll.b;
    }
#pragma unroll
    for (int j = 0; j < 4; ++j) {
      size_t boff = (size_t)(nbase + j * 16 + lr) * 512 + k0 + lk;
      bh[j] = *reinterpret_cast<const bf16x8*>(wxh + boff);
      bl[j] = *reinterpret_cast<const bf16x8*>(wxl + boff);
    }
#pragma unroll
    for (int i = 0; i < 4; ++i)
#pragma unroll
      for (int j = 0; j < 4; ++j) {
        acc[i][j] = __builtin_amdgcn_mfma_f32_16x16x32_bf16(ah[i], bh[j], acc[i][j], 0, 0, 0);
        acc[i][j] = __builtin_amdgcn_mfma_f32_16x16x32_bf16(ah[i], bl[j], acc[i][j], 0, 0, 0);
        acc[i][j] = __builtin_amdgcn_mfma_f32_16x16x32_bf16(al[i], bh[j], acc[i][j], 0, 0, 0);
      }
  }

#pragma unroll
  for (int j = 0; j < 4; ++j) {
    int n = nbase + j * 16 + lr;
    float bxv = bx[n];
#pragma unroll
    for (int i = 0; i < 4; ++i)
#pragma unroll
      for (int r = 0; r < 4; ++r) {
        int m = mbase + i * 16 + (l >> 4) * 4 + r;
        out[(size_t)m * 1024 + n] = acc[i][j][r] + bxv;
      }
  }
}

// Persistent recurrence — R13 protocol, A-burst as ONE asm mega-block.
__global__ __launch_bounds__(512, 1) void rnn_persistent(
    const ushort* __restrict__ whh,  // [1024][1024]
    const ushort* __restrict__ whl,
    ushort* __restrict__ hb,         // [2 parity][2 hi/lo][BH]
    float* __restrict__ out,         // [512][BH] (xproj in, h out)
    uint* __restrict__ flags)        // [4][64]
{
  __shared__ float lds[8 * 32 * 17];         // 17408 B, stride-17 pad
  const int wg = blockIdx.x;                 // 0..255
  const int xc = wg & 7, yy = wg >> 3;
  const int mb = xc & 3;
  const int nb = ((xc >> 2) << 5) + yy;      // 0..63
  const int tid = threadIdx.x;
  const int q = tid >> 6;                    // k-slice 0..7
  const int l = tid & 63;
  const int lr = l & 15, lk = (l >> 4) * 8;
  const int kbase = q * 128 + lk;
  const int row0 = (l >> 4) * 4;

  const ushort* bph = whh + (size_t)(nb * 16 + lr) * 1024 + kbase;
  const ushort* bpl = whl + (size_t)(nb * 16 + lr) * 1024 + kbase;
  bf16x8 vBh[4], vBl[4];
#pragma unroll
  for (int kb = 0; kb < 4; ++kb) {
    vBh[kb] = *reinterpret_cast<const bf16x8*>(bph + kb * 32);
    vBl[kb] = *reinterpret_cast<const bf16x8*>(bpl + kb * 32);
  }

  const size_t aoff = (size_t)(mb * 32 + lr) * 1024 + kbase;
  const ushort* planeA0 = hb + aoff;            // parity 0 hi
  const ushort* planeA1 = hb + 2 * BH + aoff;   // parity 1 hi

  const int em = tid >> 4, en = tid & 15;
  const size_t eidx = (size_t)(mb * 32 + em) * 1024 + nb * 16 + en;

  const uint* gate_ptr = flags + (mb << 6) + (q << 3) + (l & 7);
  uint* my_flag = flags + (mb << 6) + nb;

  for (int t = 0; t < L_SEQ; ++t) {
    float* xpt = out + (size_t)t * BH;
    const float xpv = xpt[eidx];             // prefetch; overlaps gate wait
    float hval;

    if (t > 0) {
      const uint tgt = (uint)t;
      for (uint spin = 0; spin < (1u << 20); ++spin) {
        uint f;
        asm volatile("global_load_dword %0, %1, off sc0 sc1\n\t"
                     "s_waitcnt vmcnt(0)"
                     : "=v"(f) : "v"(gate_ptr) : "memory");
        if (__all((int)(f >= tgt))) break;
        __builtin_amdgcn_s_sleep(1);
      }
      __builtin_amdgcn_sched_barrier(0);     // nothing drifts above the gate

      // A-burst: ONE asm block, 16 loads in provably-full flight.
      const ushort* ah  = ((t - 1) & 1) ? planeA1 : planeA0;
      const ushort* al  = ah + BH;
      const ushort* ah2 = ah + 16 * 1024;    // +32KB: beyond imm range
      const ushort* al2 = al + 16 * 1024;
      bf16x8 vA0h[4], vA0l[4], vA1h[4], vA1l[4];
      asm volatile(
        "global_load_dwordx4 %0, %16, off sc0 sc1\n\t"
        "global_load_dwordx4 %1, %16, off offset:64 sc0 sc1\n\t"
        "global_load_dwordx4 %2, %16, off offset:128 sc0 sc1\n\t"
        "global_load_dwordx4 %3, %16, off offset:192 sc0 sc1\n\t"
        "global_load_dwordx4 %4, %17, off sc0 sc1\n\t"
        "global_load_dwordx4 %5, %17, off offset:64 sc0 sc1\n\t"
        "global_load_dwordx4 %6, %17, off offset:128 sc0 sc1\n\t"
        "global_load_dwordx4 %7, %17, off offset:192 sc0 sc1\n\t"
        "global_load_dwordx4 %8, %18, off sc0 sc1\n\t"
        "global_load_dwordx4 %9, %18, off offset:64 sc0 sc1\n\t"
        "global_load_dwordx4 %10, %18, off offset:128 sc0 sc1\n\t"
        "global_load_dwordx4 %11, %18, off offset:192 sc0 sc1\n\t"
        "global_load_dwordx4 %12, %19, off sc0 sc1\n\t"
        "global_load_dwordx4 %13, %19, off offset:64 sc0 sc1\n\t"
        "global_load_dwordx4 %14, %19, off offset:128 sc0 sc1\n\t"
        "global_load_dwordx4 %15, %19, off offset:192 sc0 sc1\n\t"
        "s_waitcnt vmcnt(0)"
        : "=&v"(vA0h[0]), "=&v"(vA0h[1]), "=&v"(vA0h[2]), "=&v"(vA0h[3]),
          "=&v"(vA0l[0]), "=&v"(vA0l[1]), "=&v"(vA0l[2]), "=&v"(vA0l[3]),
          "=&v"(vA1h[0]), "=&v"(vA1h[1]), "=&v"(vA1h[2]), "=&v"(vA1h[3]),
          "=&v"(vA1l[0]), "=&v"(vA1l[1]), "=&v"(vA1l[2]), "=&v"(vA1l[3])
        : "v"(ah), "v"(al), "v"(ah2), "v"(al2)
        : "memory");
      __builtin_amdgcn_sched_barrier(0);     // rule #18: no consumer hoists

      f32x4 acc0 = {0.f, 0.f, 0.f, 0.f};
      f32x4 acc1 = {0.f, 0.f, 0.f, 0.f};
#pragma unroll
      for (int kb = 0; kb < 4; ++kb) {
        acc0 = __builtin_amdgcn_mfma_f32_16x16x32_bf16(vA0h[kb], vBh[kb], acc0, 0, 0, 0);
        acc1 = __builtin_amdgcn_mfma_f32_16x16x32_bf16(vA1h[kb], vBh[kb], acc1, 0, 0, 0);
        acc0 = __builtin_amdgcn_mfma_f32_16x16x32_bf16(vA0h[kb], vBl[kb], acc0, 0, 0, 0);
        acc1 = __builtin_amdgcn_mfma_f32_16x16x32_bf16(vA1h[kb], vBl[kb], acc1, 0, 0, 0);
        acc0 = __builtin_amdgcn_mfma_f32_16x16x32_bf16(vA0l[kb], vBh[kb], acc0, 0, 0, 0);
        acc1 = __builtin_amdgcn_mfma_f32_16x16x32_bf16(vA1l[kb], vBh[kb], acc1, 0, 0, 0);
      }

      // Partials -> LDS. C/D layout: col = lane&15, row = (lane>>4)*4 + r.
#pragma unroll
      for (int r = 0; r < 4; ++r) {
        lds[q * 544 + (row0 + r) * 17 + lr]      = acc0[r];
        lds[q * 544 + (16 + row0 + r) * 17 + lr] = acc1[r];
      }
      __syncthreads();   // all waves' partials in LDS (=> all gates passed)

      float s = 0.f;
#pragma unroll
      for (int qq = 0; qq < 8; ++qq) s += lds[qq * 544 + em * 17 + en];
      hval = fast_tanh(s + xpv);
    } else {
      hval = fast_tanh(xpv);
    }

    // Release path: bf16 hi/lo stores -> drain -> WG sync -> flag.
    ushort hhi = f2bf(hval);
    ushort hlo = f2bf(hval - bf2f(hhi));
    ushort* hcur = hb + (size_t)((t & 1) * 2) * BH;
    stg2_sc(hcur + eidx, (uint)hhi);
    stg2_sc(hcur + BH + eidx, (uint)hlo);
    asm volatile("s_waitcnt vmcnt(0)" ::: "memory");
    __syncthreads();   // also protects LDS against next step's overwrite
    if (tid == 0) stg4_sc(my_flag, (uint)(t + 1));

    // Off the critical path: fp32 h into d_out (never read by consumers).
    xpt[eidx] = hval;
  }
}

extern "C" void kernel_launch(void* const* d_in, const int* in_sizes, int n_in,
                              void* d_out, int out_size, void* d_ws, size_t ws_size,
                              hipStream_t stream) {
  const float* x  = (const float*)d_in[0];   // [512][128][512]
  const float* Wx = (const float*)d_in[1];   // [1024][512]
  const float* bx = (const float*)d_in[2];   // [1024]
  const float* Wh = (const float*)d_in[3];   // [1024][1024]
  float* out = (float*)d_out;                // [512][128][1024]
  ushort* ws = (ushort*)d_ws;

  ushort* whh = ws + WS_WHH;
  ushort* whl = ws + WS_WHL;
  ushort* wxh = ws + WS_WXH;
  ushort* wxl = ws + WS_WXL;
  ushort* hb  = ws + WS_HB;                  // [2][2][BH]
  uint* flags = (uint*)(ws + WS_CNT);

  split_kernel<<<dim3(2048), dim3(256), 0, stream>>>(Wh, Wx, ws, flags);
  xproj_kernel<<<dim3(2048), dim3(512), 0, stream>>>(x, wxh, wxl, bx, out);
  rnn_persistent<<<dim3(256), dim3(512), 0, stream>>>(whh, whl, hb, out, flags);
}